// Round 9
// baseline (188.090 us; speedup 1.0000x reference)
//
#include <hip/hip_runtime.h>
#include <hip/hip_bf16.h>
#include <math.h>

// Problem constants (from reference)
#define B_SZ     16
#define N_PTS    8192
#define NPOINT   2048
#define KNBR     32
#define D_FEAT   61
#define C_IN     64            // D_FEAT + 3
#define P_BINS   5
#define C_OUT    128
#define M_ROWS   (B_SZ * NPOINT)          // 32768
#define K1       (C_IN * P_BINS)          // 320
#define EPSV     1e-5f
#define NREP     16                        // stats replicas

typedef __attribute__((ext_vector_type(8))) short bf16x8;
typedef __attribute__((ext_vector_type(4))) float f32x4;

__device__ __forceinline__ unsigned short f2bf_rne(float v) {
    unsigned u = __float_as_uint(v);
    u += 0x7fffu + ((u >> 16) & 1u);
    return (unsigned short)(u >> 16);
}
__device__ __forceinline__ float bf2f(unsigned short v) {
    return __uint_as_float(((unsigned)v) << 16);
}

// Fragment-major B-side index (16x16x32 MFMA), chunk = 512 elems:
//   idx = ((c>>5)*8 + (n>>4))*512 + (((c>>3)&3)*16 + (n&15))*8 + (c&7)
__device__ __forceinline__ size_t fragB_idx(int n, int c) {
    return ((size_t)((c >> 5) * 8 + (n >> 4)) << 9) +
           ((((c >> 3) & 3) * 16 + (n & 15)) << 3) + (c & 7);
}

// ---------------------------------------------------------------------------
// Prep: blocks [0,32768): pts[B][N][64] bf16 = concat(points,xyz), XCD-pinned.
//       blocks [32768,33024): W1,W2 -> fragment-major bf16; zero stats.
// st layout (floats): [0,2048) sum1[16][128]; [2048,4096) sq1;
//                     [4096,6144) sum2; [6144,8192) sq2.
// ---------------------------------------------------------------------------
__global__ __launch_bounds__(256) void prep_kernel(
    const float* __restrict__ points, const float* __restrict__ xyz,
    const float* __restrict__ W1, const float* __restrict__ W2,
    unsigned short* __restrict__ ptsb, unsigned short* __restrict__ W1f,
    unsigned short* __restrict__ W2f, float* __restrict__ st)
{
    const int blk = blockIdx.x;
    const int tid = threadIdx.x;
    if (blk < 32768) {
        const int xcd  = blk & 7;
        const int slot = blk >> 3;                    // 0..4095
        const int b    = 2 * xcd + (slot >> 11);      // batch -> XCD b/2
        const int rin  = (slot & 2047) * 4 + (tid >> 6);
        const int row  = b * N_PTS + rin;
        const int c    = tid & 63;
        float v;
        if (c < D_FEAT) v = points[(size_t)row * D_FEAT + c];
        else            v = xyz[(size_t)row * 3 + (c - D_FEAT)];
        ptsb[((size_t)row << 6) | c] = f2bf_rne(v);
    } else {
        const int gid = (blk - 32768) * 256 + tid;    // 0..65535
        if (gid < 40960) {
            int c = gid >> 7, n = gid & 127;
            W1f[fragB_idx(n, c)] = f2bf_rne(W1[gid]);
        } else if (gid < 57344) {
            int i = gid - 40960;
            int c = i >> 7, n = i & 127;
            W2f[fragB_idx(n, c)] = f2bf_rne(W2[i]);
        } else {
            st[gid - 57344] = 0.f;
        }
    }
}

// ---------------------------------------------------------------------------
// Fused gather + GEMM1 + BN1-stats.
// Block = 16 points (one 16-row tile); wave w gathers points 4w..4w+3:
//   ballot counting-sort by bin -> sorted indices in LDS;
//   32 single-instruction table-row loads (SGPR base via readlane,
//   voffset = lane*2, zero VALU addressing, all in flight);
//   5-accumulator wave-uniform if-chain (1 v_add/elem);
//   bf16 A-fragments into LDS.
// Barrier; wave w computes cols [32w,32w+32) of x1 = feat@W1 + b1,
// stores x1 fragment-major (KCH=4), 16-replica BN1 stats.
// ---------------------------------------------------------------------------
__global__ __launch_bounds__(256) void fusedg1_kernel(
    const unsigned short* __restrict__ ptsb, const float* __restrict__ xyz,
    const float* __restrict__ lc, const int* __restrict__ nl,
    const int* __restrict__ didx, const unsigned short* __restrict__ W1f,
    const float* __restrict__ b1, unsigned short* __restrict__ x1f,
    float* __restrict__ st, float* __restrict__ newxyz)
{
    const int g    = blockIdx.x;            // 0..2047
    const int xcd  = g & 7;
    const int slot = g >> 3;                // 0..255
    const int b    = 2 * xcd + (slot >> 7); // batch -> XCD b/2
    const int tile = b * 128 + (slot & 127);
    const int wave = threadIdx.x >> 6;
    const int lane = threadIdx.x & 63;
    const int k    = lane & 31;
    const int lm   = lane & 15, kg = lane >> 4;
    const int kgl  = (lane >> 3) & 3, jl = lane & 7, khalf = lane >> 5;

    __shared__ int s_srt[4][32];
    __shared__ __align__(16) unsigned short sA[10 * 512];   // 10 KB A tile

    const unsigned short* __restrict__ tb = ptsb + (((size_t)b * N_PTS) << 6);
    const float* __restrict__ xbase = xyz + (size_t)b * N_PTS * 3;

    for (int p = 0; p < 4; ++p) {
        const int mloc = wave * 4 + p;           // row within tile
        const int bid  = tile * 16 + mloc;       // global row
        const size_t nbase = (size_t)bid * KNBR;

        const float x = lc[(nbase + k) * 3 + 0];
        const float y = lc[(nbase + k) * 3 + 1];
        const float dd = fminf(sqrtf(x * x + y * y) * (1.0f / 1.5f), 0.99f);
        int bin = (int)(dd * 5.0f);
        bin = bin > 4 ? 4 : (bin < 0 ? 0 : bin);
        const int n = nl[nbase + k];

        unsigned m0 = (unsigned)__ballot(bin == 0);
        unsigned m1 = (unsigned)__ballot(bin == 1);
        unsigned m2 = (unsigned)__ballot(bin == 2);
        unsigned m3 = (unsigned)__ballot(bin == 3);
        unsigned m4 = (unsigned)__ballot(bin == 4);
        const int c0n = __popc(m0), c1n = __popc(m1);
        const int c2n = __popc(m2), c3n = __popc(m3);
        const int e0 = c0n, e1 = e0 + c1n, e2 = e1 + c2n, e3 = e2 + c3n;

        int start = (bin > 0 ? c0n : 0) + (bin > 1 ? c1n : 0) +
                    (bin > 2 ? c2n : 0) + (bin > 3 ? c3n : 0);
        unsigned mymask = m0;
        mymask = bin == 1 ? m1 : mymask;
        mymask = bin == 2 ? m2 : mymask;
        mymask = bin == 3 ? m3 : mymask;
        mymask = bin == 4 ? m4 : mymask;
        const int pos = start + __popc(mymask & ((1u << k) - 1u));

        if (lane < 32) s_srt[wave][pos] = n;
        if (lane >= 32 && lane < 35) {
            const int di = didx[bid];
            newxyz[(size_t)bid * 3 + (lane - 32)] = xbase[(size_t)di * 3 + (lane - 32)];
        }

        const int srtv = s_srt[wave][k];   // lane-indexed; readlane below

        // 32 single-instruction row loads, all in flight (SGPR base per kk)
        unsigned short vv[32];
        #pragma unroll
        for (int kk = 0; kk < 32; ++kk) {
            const int nr = __builtin_amdgcn_readlane(srtv, kk);
            vv[kk] = tb[((size_t)nr << 6) | lane];
        }

        // 5-accumulator accumulation; run boundaries e0..e3 are wave-uniform
        float a0 = 0.f, a1 = 0.f, a2 = 0.f, a3 = 0.f, a4 = 0.f;
        #pragma unroll
        for (int kk = 0; kk < 32; ++kk) {
            const float v = bf2f(vv[kk]);
            if      (kk < e0) a0 += v;
            else if (kk < e1) a1 += v;
            else if (kk < e2) a2 += v;
            else if (kk < e3) a3 += v;
            else              a4 += v;
        }

        // A-fragment writes into LDS (ch c = bb*64 + lane, row = mloc)
        const float vals[5] = {a0, a1, a2, a3, a4};
        #pragma unroll
        for (int bb = 0; bb < 5; ++bb) {
            const int kb = bb * 2 + khalf;
            sA[kb * 512 + (kgl * 16 + mloc) * 8 + jl] = f2bf_rne(vals[bb]);
        }
    }
    __syncthreads();

    // GEMM phase: wave w -> cols [32w, 32w+32)
    f32x4 acc0 = {}, acc1 = {};
    #pragma unroll
    for (int kb = 0; kb < 10; ++kb) {
        bf16x8 a = *(const bf16x8*)&sA[kb * 512 + lane * 8];
        bf16x8 w0 = *(const bf16x8*)(W1f + ((size_t)(kb * 8 + wave * 2) << 9) + lane * 8);
        bf16x8 w1 = *(const bf16x8*)(W1f + ((size_t)(kb * 8 + wave * 2 + 1) << 9) + lane * 8);
        acc0 = __builtin_amdgcn_mfma_f32_16x16x32_bf16(a, w0, acc0, 0, 0, 0);
        acc1 = __builtin_amdgcn_mfma_f32_16x16x32_bf16(a, w1, acc1, 0, 0, 0);
    }

    const int rep = (g & (NREP - 1)) * 128;
    #pragma unroll
    for (int q = 0; q < 2; ++q) {
        const f32x4 A = q ? acc1 : acc0;
        const int col = (wave * 2 + q) * 16 + lm;
        const float bb = b1[col];
        float ls = 0.f, lq = 0.f;
        #pragma unroll
        for (int i = 0; i < 4; ++i) {
            float vv2 = A[i] + bb;
            const size_t idx = (((size_t)(tile * 4 + (col >> 5))) << 9) +
                               ((((col >> 3) & 3) * 16 + kg * 4 + i) << 3) + (col & 7);
            x1f[idx] = f2bf_rne(vv2);
            ls += vv2; lq += vv2 * vv2;
        }
        ls += __shfl_xor(ls, 16); ls += __shfl_xor(ls, 32);
        lq += __shfl_xor(lq, 16); lq += __shfl_xor(lq, 32);
        if (kg == 0) {
            atomicAdd(&st[rep + col], ls);
            atomicAdd(&st[2048 + rep + col], lq);
        }
    }
}

// ---------------------------------------------------------------------------
// GEMM2 (MFMA bf16): y = relu(BN1(x1)) @ W2 + b2, BN1 fused into A-frag load.
// Block = one 16-row tile (same g->tile map as fusedg1 so x1f reads are
// XCD-local); wave w -> cols [32w,32w+32). Grid 2048 for occupancy.
// BN2 stats into 16-replica block.
// ---------------------------------------------------------------------------
__global__ __launch_bounds__(256) void gemm2_mfma(
    const unsigned short* __restrict__ Xf,
    const float* __restrict__ st_in,
    const float* __restrict__ g1, const float* __restrict__ be1,
    const unsigned short* __restrict__ Wf, const float* __restrict__ bias,
    unsigned short* __restrict__ out, float* __restrict__ st)
{
    __shared__ float sc[128], sh[128];
    const int tid = threadIdx.x;
    if (tid < 128) {
        float s = 0.f, q = 0.f;
        #pragma unroll
        for (int r = 0; r < NREP; ++r) {
            s += st_in[r * 128 + tid];
            q += st_in[2048 + r * 128 + tid];
        }
        float mu  = s * (1.0f / (float)M_ROWS);
        float var = q * (1.0f / (float)M_ROWS) - mu * mu;
        float iv  = 1.0f / sqrtf(var + EPSV);
        float sg  = g1[tid] * iv;
        sc[tid] = sg;
        sh[tid] = be1[tid] - mu * sg;
    }
    __syncthreads();

    const int g    = blockIdx.x;            // 0..2047
    const int xcd  = g & 7;
    const int slot = g >> 3;
    const int b    = 2 * xcd + (slot >> 7);
    const int tile = b * 128 + (slot & 127);

    const int wave = tid >> 6, lane = tid & 63;
    const int lm = lane & 15, kg = lane >> 4;

    f32x4 acc0 = {}, acc1 = {};
    #pragma unroll
    for (int kb = 0; kb < 4; ++kb) {
        const int c0 = kb * 32 + kg * 8;
        bf16x8 xr = *(const bf16x8*)(Xf + (((size_t)(tile * 4 + kb)) << 9) + lane * 8);
        bf16x8 a;
        #pragma unroll
        for (int j = 0; j < 8; ++j) {
            float xv = bf2f((unsigned short)xr[j]);
            a[j] = (short)f2bf_rne(fmaxf(0.f, sc[c0 + j] * xv + sh[c0 + j]));
        }
        bf16x8 w0 = *(const bf16x8*)(Wf + ((size_t)(kb * 8 + wave * 2) << 9) + lane * 8);
        bf16x8 w1 = *(const bf16x8*)(Wf + ((size_t)(kb * 8 + wave * 2 + 1) << 9) + lane * 8);
        acc0 = __builtin_amdgcn_mfma_f32_16x16x32_bf16(a, w0, acc0, 0, 0, 0);
        acc1 = __builtin_amdgcn_mfma_f32_16x16x32_bf16(a, w1, acc1, 0, 0, 0);
    }

    const int orow = tile * 16 + kg * 4;
    const int rep = (g & (NREP - 1)) * 128;
    #pragma unroll
    for (int q = 0; q < 2; ++q) {
        const f32x4 A = q ? acc1 : acc0;
        const int col = (wave * 2 + q) * 16 + lm;
        const float bb = bias[col];
        float ls = 0.f, lq = 0.f;
        #pragma unroll
        for (int i = 0; i < 4; ++i) {
            float v = A[i] + bb;
            out[(size_t)(orow + i) * C_OUT + col] = f2bf_rne(v);
            ls += v; lq += v * v;
        }
        ls += __shfl_xor(ls, 16); ls += __shfl_xor(ls, 32);
        lq += __shfl_xor(lq, 16); lq += __shfl_xor(lq, 32);
        if (kg == 0) {
            atomicAdd(&st[4096 + rep + col], ls);
            atomicAdd(&st[6144 + rep + col], lq);
        }
    }
}

// ---------------------------------------------------------------------------
// Final: new_points = relu(BN2(y)), y bf16 row-major, out f32.
// ---------------------------------------------------------------------------
__global__ __launch_bounds__(256) void out_kernel(
    const unsigned short* __restrict__ Y, const float* __restrict__ st,
    const float* __restrict__ g2, const float* __restrict__ be2,
    float* __restrict__ out)
{
    __shared__ float sc[128], sh[128];
    const int tid = threadIdx.x;
    if (tid < 128) {
        float s = 0.f, q = 0.f;
        #pragma unroll
        for (int r = 0; r < NREP; ++r) {
            s += st[4096 + r * 128 + tid];
            q += st[6144 + r * 128 + tid];
        }
        float mu  = s * (1.0f / (float)M_ROWS);
        float var = q * (1.0f / (float)M_ROWS) - mu * mu;
        float iv  = 1.0f / sqrtf(var + EPSV);
        float sg  = g2[tid] * iv;
        sc[tid] = sg;
        sh[tid] = be2[tid] - mu * sg;
    }
    __syncthreads();

    const size_t e8 = (size_t)blockIdx.x * 256 + tid;   // ushort8 index
    bf16x8 v = ((const bf16x8*)Y)[e8];
    const int cb = (int)((e8 * 8) & 127);
    float4 r0, r1;
    r0.x = fmaxf(0.f, sc[cb + 0] * bf2f((unsigned short)v[0]) + sh[cb + 0]);
    r0.y = fmaxf(0.f, sc[cb + 1] * bf2f((unsigned short)v[1]) + sh[cb + 1]);
    r0.z = fmaxf(0.f, sc[cb + 2] * bf2f((unsigned short)v[2]) + sh[cb + 2]);
    r0.w = fmaxf(0.f, sc[cb + 3] * bf2f((unsigned short)v[3]) + sh[cb + 3]);
    r1.x = fmaxf(0.f, sc[cb + 4] * bf2f((unsigned short)v[4]) + sh[cb + 4]);
    r1.y = fmaxf(0.f, sc[cb + 5] * bf2f((unsigned short)v[5]) + sh[cb + 5]);
    r1.z = fmaxf(0.f, sc[cb + 6] * bf2f((unsigned short)v[6]) + sh[cb + 6]);
    r1.w = fmaxf(0.f, sc[cb + 7] * bf2f((unsigned short)v[7]) + sh[cb + 7]);
    ((float4*)out)[e8 * 2]     = r0;
    ((float4*)out)[e8 * 2 + 1] = r1;
}

// ---------------------------------------------------------------------------
extern "C" void kernel_launch(void* const* d_in, const int* in_sizes, int n_in,
                              void* d_out, int out_size, void* d_ws, size_t ws_size,
                              hipStream_t stream)
{
    const float* xyz    = (const float*)d_in[0];
    const float* points = (const float*)d_in[1];
    const float* lc     = (const float*)d_in[2];
    const int*   nl     = (const int*)d_in[3];
    // d_in[4] parameter_list: unused
    const int*   didx   = (const int*)d_in[5];
    const float* W1     = (const float*)d_in[6];
    const float* b1     = (const float*)d_in[7];
    const float* g1     = (const float*)d_in[8];
    const float* be1    = (const float*)d_in[9];
    const float* W2     = (const float*)d_in[10];
    const float* b2     = (const float*)d_in[11];
    const float* g2     = (const float*)d_in[12];
    const float* be2    = (const float*)d_in[13];

    float* out = (float*)d_out;
    char*  ws  = (char*)d_ws;

    // workspace layout (bytes), total 33,701,888:
    unsigned short* ptsb = (unsigned short*)ws;                    // 16,777,216 B
    unsigned short* x1f  = (unsigned short*)(ws + 16777216);       //  8,388,608 B
    unsigned short* yb   = (unsigned short*)(ws + 25165824);       //  8,388,608 B
    unsigned short* W1f  = (unsigned short*)(ws + 33554432);       //     81,920 B
    unsigned short* W2f  = (unsigned short*)(ws + 33636352);       //     32,768 B
    float*          st   = (float*)(ws + 33669120);                //     32,768 B

    prep_kernel<<<32768 + 256, 256, 0, stream>>>(points, xyz, W1, W2,
                                                 ptsb, W1f, W2f, st);
    fusedg1_kernel<<<M_ROWS / 16, 256, 0, stream>>>(ptsb, xyz, lc, nl, didx,
                                                    W1f, b1, x1f, st, out);
    gemm2_mfma<<<M_ROWS / 16, 256, 0, stream>>>(x1f, st, g1, be1,
                                                W2f, b2, yb, st);
    out_kernel<<<(M_ROWS * C_OUT) / (256 * 8), 256, 0, stream>>>(
        yb, st, g2, be2, out + (size_t)M_ROWS * 3);
}

// Round 11
// 186.588 us; speedup vs baseline: 1.0081x; 1.0081x over previous
//
#include <hip/hip_runtime.h>
#include <hip/hip_bf16.h>
#include <math.h>

// Problem constants (from reference)
#define B_SZ     16
#define N_PTS    8192
#define NPOINT   2048
#define KNBR     32
#define D_FEAT   61
#define C_IN     64            // D_FEAT + 3
#define P_BINS   5
#define C_OUT    128
#define M_ROWS   (B_SZ * NPOINT)          // 32768
#define K1       (C_IN * P_BINS)          // 320
#define EPSV     1e-5f

typedef __attribute__((ext_vector_type(8))) short bf16x8;
typedef __attribute__((ext_vector_type(4))) float f32x4;

__device__ __forceinline__ unsigned short f2bf_rne(float v) {
    unsigned u = __float_as_uint(v);
    u += 0x7fffu + ((u >> 16) & 1u);
    return (unsigned short)(u >> 16);
}
__device__ __forceinline__ float bf2f(unsigned short v) {
    return __uint_as_float(((unsigned)v) << 16);
}

// Fragment-major B-side index (16x16x32 MFMA), chunk = 512 elems:
//   idx = ((c>>5)*8 + (n>>4))*512 + (((c>>3)&3)*16 + (n&15))*8 + (c&7)
__device__ __forceinline__ size_t fragB_idx(int n, int c) {
    return ((size_t)((c >> 5) * 8 + (n >> 4)) << 9) +
           ((((c >> 3) & 3) * 16 + (n & 15)) << 3) + (c & 7);
}

// ---------------------------------------------------------------------------
// Prep: blocks [0,32768): pts[B][N][64] bf16 = concat(points,xyz), XCD-pinned.
//       blocks [32768,33024): W1,W2 -> fragment-major bf16; zero stats.
// st layout (floats): [0,1024) sum1[8][128]; [1024,2048) sq1;
//                     [2048,3072) sum2; [3072,4096) sq2.
// ---------------------------------------------------------------------------
__global__ __launch_bounds__(256) void prep_kernel(
    const float* __restrict__ points, const float* __restrict__ xyz,
    const float* __restrict__ W1, const float* __restrict__ W2,
    unsigned short* __restrict__ ptsb, unsigned short* __restrict__ W1f,
    unsigned short* __restrict__ W2f, float* __restrict__ st)
{
    const int blk = blockIdx.x;
    const int tid = threadIdx.x;
    if (blk < 32768) {
        const int xcd  = blk & 7;
        const int slot = blk >> 3;                    // 0..4095
        const int b    = 2 * xcd + (slot >> 11);      // batch -> XCD b/2
        const int rin  = (slot & 2047) * 4 + (tid >> 6);
        const int row  = b * N_PTS + rin;
        const int c    = tid & 63;
        float v;
        if (c < D_FEAT) v = points[(size_t)row * D_FEAT + c];
        else            v = xyz[(size_t)row * 3 + (c - D_FEAT)];
        ptsb[((size_t)row << 6) | c] = f2bf_rne(v);
    } else {
        const int gid = (blk - 32768) * 256 + tid;    // 0..65535
        if (gid < 40960) {
            int c = gid >> 7, n = gid & 127;
            W1f[fragB_idx(n, c)] = f2bf_rne(W1[gid]);
        } else if (gid < 57344) {
            int i = gid - 40960;
            int c = i >> 7, n = i & 127;
            W2f[fragB_idx(n, c)] = f2bf_rne(W2[i]);
        } else if (gid < 61440) {
            st[gid - 57344] = 0.f;
        }
    }
}

// ---------------------------------------------------------------------------
// Fused gather + GEMM1 + BN1-stats.
// Block = 16 points (one 16-row tile); wave w gathers points 4w..4w+3:
//   ballot counting-sort by radial bin -> sorted indices (LDS);
//   stage 32 sorted table rows into LDS with 4 coalesced dwordx4/point
//   (8 rows per instruction, deep latency overlap);
//   5-accumulator wave-uniform if-chain over staged rows (lane = channel,
//   contiguous conflict-free LDS row reads, ~2 ops/element);
//   bf16 A-fragments into LDS.
// Barrier; wave w computes cols [32w,32w+32) of x1 = feat@W1 + b1,
// stores x1 fragment-major (KCH=4), 8-replica BN1 stats.
// ---------------------------------------------------------------------------
__global__ __launch_bounds__(256) void fusedg1_kernel(
    const unsigned short* __restrict__ ptsb, const float* __restrict__ xyz,
    const float* __restrict__ lc, const int* __restrict__ nl,
    const int* __restrict__ didx, const unsigned short* __restrict__ W1f,
    const float* __restrict__ b1, unsigned short* __restrict__ x1f,
    float* __restrict__ st, float* __restrict__ newxyz)
{
    const int g    = blockIdx.x;            // 0..2047
    const int xcd  = g & 7;
    const int slot = g >> 3;                // 0..255
    const int b    = 2 * xcd + (slot >> 7); // batch -> XCD b/2
    const int tile = b * 128 + (slot & 127);
    const int wave = threadIdx.x >> 6;
    const int lane = threadIdx.x & 63;
    const int k    = lane & 31;
    const int lm   = lane & 15, kg = lane >> 4;
    const int kgl  = (lane >> 3) & 3, jl = lane & 7, khalf = lane >> 5;

    __shared__ int s_srt[4][32];
    __shared__ __align__(16) unsigned short s_stage[4][32][64];   // 16 KB
    __shared__ __align__(16) unsigned short sA[10 * 512];         // 10 KB

    const unsigned short* __restrict__ tb = ptsb + (((size_t)b * N_PTS) << 6);
    const float* __restrict__ xbase = xyz + (size_t)b * N_PTS * 3;

    for (int p = 0; p < 4; ++p) {
        const int mloc = wave * 4 + p;           // row within tile
        const int bid  = tile * 16 + mloc;       // global row
        const size_t nbase = (size_t)bid * KNBR;

        const float x = lc[(nbase + k) * 3 + 0];
        const float y = lc[(nbase + k) * 3 + 1];
        const float dd = fminf(sqrtf(x * x + y * y) * (1.0f / 1.5f), 0.99f);
        int bin = (int)(dd * 5.0f);
        bin = bin > 4 ? 4 : (bin < 0 ? 0 : bin);
        const int n = nl[nbase + k];

        unsigned m0 = (unsigned)__ballot(bin == 0);
        unsigned m1 = (unsigned)__ballot(bin == 1);
        unsigned m2 = (unsigned)__ballot(bin == 2);
        unsigned m3 = (unsigned)__ballot(bin == 3);
        unsigned m4 = (unsigned)__ballot(bin == 4);
        const int c0n = __popc(m0), c1n = __popc(m1);
        const int c2n = __popc(m2), c3n = __popc(m3);
        const int e0 = c0n, e1 = e0 + c1n, e2 = e1 + c2n, e3 = e2 + c3n;

        int start = (bin > 0 ? c0n : 0) + (bin > 1 ? c1n : 0) +
                    (bin > 2 ? c2n : 0) + (bin > 3 ? c3n : 0);
        unsigned mymask = m0;
        mymask = bin == 1 ? m1 : mymask;
        mymask = bin == 2 ? m2 : mymask;
        mymask = bin == 3 ? m3 : mymask;
        mymask = bin == 4 ? m4 : mymask;
        const int pos = start + __popc(mymask & ((1u << k) - 1u));

        if (lane < 32) s_srt[wave][pos] = n;
        if (lane >= 32 && lane < 35) {
            const int di = didx[bid];
            newxyz[(size_t)bid * 3 + (lane - 32)] = xbase[(size_t)di * 3 + (lane - 32)];
        }

        // stage 32 sorted rows: lane (r = lane>>3, j7 = lane&7) -> 16B chunks;
        // one dwordx4 instruction stages 8 full rows (1 KB), 4 instrs in flight
        const int r = lane >> 3, j7 = lane & 7;
        #pragma unroll
        for (int g4 = 0; g4 < 4; ++g4) {
            const int nr = s_srt[wave][g4 * 8 + r];
            bf16x8 row = *(const bf16x8*)(tb + ((size_t)nr << 6) + j7 * 8);
            *(bf16x8*)&s_stage[wave][g4 * 8 + r][j7 * 8] = row;
        }

        // 5-accumulator accumulation; run boundaries e0..e3 wave-uniform (SGPR)
        float a0 = 0.f, a1 = 0.f, a2 = 0.f, a3 = 0.f, a4 = 0.f;
        #pragma unroll
        for (int kk = 0; kk < 32; ++kk) {
            const float v = bf2f(s_stage[wave][kk][lane]);
            if      (kk < e0) a0 += v;
            else if (kk < e1) a1 += v;
            else if (kk < e2) a2 += v;
            else if (kk < e3) a3 += v;
            else              a4 += v;
        }

        // A-fragment writes into LDS (ch c = bb*64 + lane, row = mloc)
        const float vals[5] = {a0, a1, a2, a3, a4};
        #pragma unroll
        for (int bb = 0; bb < 5; ++bb) {
            const int kb = bb * 2 + khalf;
            sA[kb * 512 + (kgl * 16 + mloc) * 8 + jl] = f2bf_rne(vals[bb]);
        }
    }
    __syncthreads();

    // GEMM phase: wave w -> cols [32w, 32w+32)
    f32x4 acc0 = {}, acc1 = {};
    #pragma unroll
    for (int kb = 0; kb < 10; ++kb) {
        bf16x8 a = *(const bf16x8*)&sA[kb * 512 + lane * 8];
        bf16x8 w0 = *(const bf16x8*)(W1f + ((size_t)(kb * 8 + wave * 2) << 9) + lane * 8);
        bf16x8 w1 = *(const bf16x8*)(W1f + ((size_t)(kb * 8 + wave * 2 + 1) << 9) + lane * 8);
        acc0 = __builtin_amdgcn_mfma_f32_16x16x32_bf16(a, w0, acc0, 0, 0, 0);
        acc1 = __builtin_amdgcn_mfma_f32_16x16x32_bf16(a, w1, acc1, 0, 0, 0);
    }

    const int rep = (g & 7) * 128;
    #pragma unroll
    for (int q = 0; q < 2; ++q) {
        const f32x4 A = q ? acc1 : acc0;
        const int col = (wave * 2 + q) * 16 + lm;
        const float bb = b1[col];
        float ls = 0.f, lq = 0.f;
        #pragma unroll
        for (int i = 0; i < 4; ++i) {
            float vv2 = A[i] + bb;
            const size_t idx = (((size_t)(tile * 4 + (col >> 5))) << 9) +
                               ((((col >> 3) & 3) * 16 + kg * 4 + i) << 3) + (col & 7);
            x1f[idx] = f2bf_rne(vv2);
            ls += vv2; lq += vv2 * vv2;
        }
        ls += __shfl_xor(ls, 16); ls += __shfl_xor(ls, 32);
        lq += __shfl_xor(lq, 16); lq += __shfl_xor(lq, 32);
        if (kg == 0) {
            atomicAdd(&st[rep + col], ls);
            atomicAdd(&st[1024 + rep + col], lq);
        }
    }
}

// ---------------------------------------------------------------------------
// GEMM2 (MFMA bf16): y = relu(BN1(x1)) @ W2 + b2, BN1 fused into A-frag load.
// A from x1 frag-major (KCH=4), B from W2 frag-major. y row-major bf16.
// BN2 stats into 8-replica block. (r8-proven version, grid 512.)
// ---------------------------------------------------------------------------
__global__ __launch_bounds__(256) void gemm2_mfma(
    const unsigned short* __restrict__ Xf,
    const float* __restrict__ st_in,
    const float* __restrict__ g1, const float* __restrict__ be1,
    const unsigned short* __restrict__ Wf, const float* __restrict__ bias,
    unsigned short* __restrict__ out, float* __restrict__ st)
{
    __shared__ float sc[128], sh[128];
    __shared__ float s_s[4][128], s_q[4][128];
    const int tid = threadIdx.x;
    if (tid < 128) {
        float s = 0.f, q = 0.f;
        #pragma unroll
        for (int r = 0; r < 8; ++r) {
            s += st_in[r * 128 + tid];
            q += st_in[1024 + r * 128 + tid];
        }
        float mu  = s * (1.0f / (float)M_ROWS);
        float var = q * (1.0f / (float)M_ROWS) - mu * mu;
        float iv  = 1.0f / sqrtf(var + EPSV);
        float sg  = g1[tid] * iv;
        sc[tid] = sg;
        sh[tid] = be1[tid] - mu * sg;
    }
    __syncthreads();

    const int g    = blockIdx.x;
    const int xcd  = g & 7;
    const int slot = g >> 3;
    const int bb_  = 2 * xcd + (slot >> 5);
    const int tile = (bb_ * 32 + (slot & 31)) * 4 + (tid >> 6);

    const int wave = tid >> 6, lane = tid & 63;
    const int lm = lane & 15, kg = lane >> 4;

    f32x4 acc[8] = {};
    #pragma unroll
    for (int kb = 0; kb < 4; ++kb) {
        const int c0 = kb * 32 + kg * 8;
        bf16x8 xr = *(const bf16x8*)(Xf + (((size_t)(tile * 4 + kb)) << 9) + lane * 8);
        bf16x8 a;
        #pragma unroll
        for (int j = 0; j < 8; ++j) {
            float xv = bf2f((unsigned short)xr[j]);
            a[j] = (short)f2bf_rne(fmaxf(0.f, sc[c0 + j] * xv + sh[c0 + j]));
        }
        #pragma unroll
        for (int nf = 0; nf < 8; ++nf) {
            bf16x8 bfr = *(const bf16x8*)(Wf + (((size_t)(kb * 8 + nf)) << 9) + lane * 8);
            acc[nf] = __builtin_amdgcn_mfma_f32_16x16x32_bf16(a, bfr, acc[nf], 0, 0, 0);
        }
    }

    const int orow = tile * 16 + kg * 4;
    #pragma unroll
    for (int nf = 0; nf < 8; ++nf) {
        const int col = nf * 16 + lm;
        const float bb = bias[col];
        float ls = 0.f, lq = 0.f;
        #pragma unroll
        for (int i = 0; i < 4; ++i) {
            float v = acc[nf][i] + bb;
            out[(size_t)(orow + i) * C_OUT + col] = f2bf_rne(v);
            ls += v; lq += v * v;
        }
        ls += __shfl_xor(ls, 16); ls += __shfl_xor(ls, 32);
        lq += __shfl_xor(lq, 16); lq += __shfl_xor(lq, 32);
        if (kg == 0) { s_s[wave][col] = ls; s_q[wave][col] = lq; }
    }
    __syncthreads();
    if (tid < 128) {
        const int rep = (g & 7) * 128;
        float ts = s_s[0][tid] + s_s[1][tid] + s_s[2][tid] + s_s[3][tid];
        float tq = s_q[0][tid] + s_q[1][tid] + s_q[2][tid] + s_q[3][tid];
        atomicAdd(&st[2048 + rep + tid], ts);
        atomicAdd(&st[3072 + rep + tid], tq);
    }
}

// ---------------------------------------------------------------------------
// Final: new_points = relu(BN2(y)), y bf16 row-major, out f32.
// ---------------------------------------------------------------------------
__global__ __launch_bounds__(256) void out_kernel(
    const unsigned short* __restrict__ Y, const float* __restrict__ st,
    const float* __restrict__ g2, const float* __restrict__ be2,
    float* __restrict__ out)
{
    __shared__ float sc[128], sh[128];
    const int tid = threadIdx.x;
    if (tid < 128) {
        float s = 0.f, q = 0.f;
        #pragma unroll
        for (int r = 0; r < 8; ++r) {
            s += st[2048 + r * 128 + tid];
            q += st[3072 + r * 128 + tid];
        }
        float mu  = s * (1.0f / (float)M_ROWS);
        float var = q * (1.0f / (float)M_ROWS) - mu * mu;
        float iv  = 1.0f / sqrtf(var + EPSV);
        float sg  = g2[tid] * iv;
        sc[tid] = sg;
        sh[tid] = be2[tid] - mu * sg;
    }
    __syncthreads();

    const size_t e8 = (size_t)blockIdx.x * 256 + tid;   // ushort8 index
    bf16x8 v = ((const bf16x8*)Y)[e8];
    const int cb = (int)((e8 * 8) & 127);
    float4 r0, r1;
    r0.x = fmaxf(0.f, sc[cb + 0] * bf2f((unsigned short)v[0]) + sh[cb + 0]);
    r0.y = fmaxf(0.f, sc[cb + 1] * bf2f((unsigned short)v[1]) + sh[cb + 1]);
    r0.z = fmaxf(0.f, sc[cb + 2] * bf2f((unsigned short)v[2]) + sh[cb + 2]);
    r0.w = fmaxf(0.f, sc[cb + 3] * bf2f((unsigned short)v[3]) + sh[cb + 3]);
    r1.x = fmaxf(0.f, sc[cb + 4] * bf2f((unsigned short)v[4]) + sh[cb + 4]);
    r1.y = fmaxf(0.f, sc[cb + 5] * bf2f((unsigned short)v[5]) + sh[cb + 5]);
    r1.z = fmaxf(0.f, sc[cb + 6] * bf2f((unsigned short)v[6]) + sh[cb + 6]);
    r1.w = fmaxf(0.f, sc[cb + 7] * bf2f((unsigned short)v[7]) + sh[cb + 7]);
    ((float4*)out)[e8 * 2]     = r0;
    ((float4*)out)[e8 * 2 + 1] = r1;
}

// ---------------------------------------------------------------------------
extern "C" void kernel_launch(void* const* d_in, const int* in_sizes, int n_in,
                              void* d_out, int out_size, void* d_ws, size_t ws_size,
                              hipStream_t stream)
{
    const float* xyz    = (const float*)d_in[0];
    const float* points = (const float*)d_in[1];
    const float* lc     = (const float*)d_in[2];
    const int*   nl     = (const int*)d_in[3];
    // d_in[4] parameter_list: unused
    const int*   didx   = (const int*)d_in[5];
    const float* W1     = (const float*)d_in[6];
    const float* b1     = (const float*)d_in[7];
    const float* g1     = (const float*)d_in[8];
    const float* be1    = (const float*)d_in[9];
    const float* W2     = (const float*)d_in[10];
    const float* b2     = (const float*)d_in[11];
    const float* g2     = (const float*)d_in[12];
    const float* be2    = (const float*)d_in[13];

    float* out = (float*)d_out;
    char*  ws  = (char*)d_ws;

    // workspace layout (bytes):
    unsigned short* ptsb = (unsigned short*)ws;                    // 16,777,216 B
    unsigned short* x1f  = (unsigned short*)(ws + 16777216);       //  8,388,608 B
    unsigned short* yb   = (unsigned short*)(ws + 25165824);       //  8,388,608 B
    unsigned short* W1f  = (unsigned short*)(ws + 33554432);       //     81,920 B
    unsigned short* W2f  = (unsigned short*)(ws + 33636352);       //     32,768 B
    float*          st   = (float*)(ws + 33669120);                //     16,384 B

    prep_kernel<<<32768 + 256, 256, 0, stream>>>(points, xyz, W1, W2,
                                                 ptsb, W1f, W2f, st);
    fusedg1_kernel<<<M_ROWS / 16, 256, 0, stream>>>(ptsb, xyz, lc, nl, didx,
                                                    W1f, b1, x1f, st, out);
    gemm2_mfma<<<M_ROWS / 64, 256, 0, stream>>>(x1f, st, g1, be1,
                                                W2f, b2, yb, st);
    out_kernel<<<(M_ROWS * C_OUT) / (256 * 8), 256, 0, stream>>>(
        yb, st, g2, be2, out + (size_t)M_ROWS * 3);
}